// Round 1
// baseline (124.370 us; speedup 1.0000x reference)
//
#include <hip/hip_runtime.h>
#include <math.h>

#define N_ATOMS 512
#define NSUB 768                 // sub-buckets over [0, L/2); delta = 12/768 = 0.015625
#define NMOM 5                   // moments M0..M4 (Sum 1, eps, eps^2, eps^3, eps^4)
#define NM (NMOM * NSUB)         // 3840 floats per partial histogram
#define RCHUNK 32                // reduction chunks
#define WIN_EVAL 0.75f           // eval window; exp(-50*0.75^2) ~ 7e-13
#define NB_MAX 128               // max sub-buckets per bin window (1.5*64+2 = 98 for L=24)

__global__ void zero_kernel(float* p, int n) {
    int t = blockIdx.x * blockDim.x + threadIdx.x;
    if (t < n) p[t] = 0.0f;
}

// Grid: F * 64 blocks, 256 threads. Block = (frame, 4 bow-tie row-pairs) = 2048 pairs.
// Accumulates per-sub-bucket moment sums of eps = d - c_b in LDS, flushes to part[].
__global__ __launch_bounds__(256) void pair_kernel(
    const float* __restrict__ traj, const float* __restrict__ cell,
    float* __restrict__ part, int atomic_mode)
{
    __shared__ float2 qxy[N_ATOMS];
    __shared__ float  qzs[N_ATOMS];
    __shared__ float  M[NM];     // SoA: M[m*NSUB + b] -> bank = b&31, ~2-way conflicts

    const int frame = blockIdx.x >> 6;
    const int sub   = blockIdx.x & 63;
    const int tid   = threadIdx.x;

    const float* q = traj + (size_t)frame * (N_ATOMS * 3);
    for (int a = tid; a < N_ATOMS; a += 256) {
        qxy[a] = make_float2(q[3 * a + 0], q[3 * a + 1]);
        qzs[a] = q[3 * a + 2];
    }
    for (int i = tid; i < NM; i += 256) M[i] = 0.0f;
    __syncthreads();

    const float L = cell[0];
    const float invL = 1.0f / L;
    const float cutoff_sq = 0.25f * L * L;
    const float inv_delta = (2.0f * (float)NSUB) / L;
    const float delta = L / (2.0f * (float)NSUB);

    #pragma unroll
    for (int s = 0; s < 8; ++s) {
        const int qidx = s * 256 + tid;            // [0, 2048)
        const int rp   = sub * 4 + (qidx >> 9);    // row-pair [0, 256)
        const int qq   = qidx & 511;
        const int lenA = 511 - rp;                 // row rp: j in (rp, 511]
        const bool inA = qq < lenA;
        const int i = inA ? rp : (510 - rp);       // partner row 510-rp
        const int j = inA ? (rp + 1 + qq) : qq;    // row B: j == qq (exact)
        const bool vp = !(rp == 255 && !inA);      // rp==255 pairs with itself: half only

        const float2 pj = qxy[j];
        const float2 pi = qxy[i];
        float dx = pj.x - pi.x;
        float dy = pj.y - pi.y;
        float dz = qzs[j] - qzs[i];
        dx -= L * floorf(dx * invL + 0.5f);
        dy -= L * floorf(dy * invL + 0.5f);
        dz -= L * floorf(dz * invL + 0.5f);
        const float d2 = dx * dx + dy * dy + dz * dz;

        if (vp && d2 < cutoff_sq && d2 != 0.0f) {
            const float d = sqrtf(d2);
            int b = (int)(d * inv_delta);
            if (b > NSUB - 1) b = NSUB - 1;
            const float eps = fmaf(-((float)b + 0.5f), delta, d);  // d - (b+0.5)*delta
            const float e2 = eps * eps;
            atomicAdd(&M[b],            1.0f);
            atomicAdd(&M[NSUB + b],     eps);
            atomicAdd(&M[2 * NSUB + b], e2);
            atomicAdd(&M[3 * NSUB + b], e2 * eps);
            atomicAdd(&M[4 * NSUB + b], e2 * e2);
        }
    }
    __syncthreads();

    if (atomic_mode) {
        float* dst = part + (size_t)(blockIdx.x & 15) * NM;
        for (int i = tid; i < NM; i += 256) atomicAdd(&dst[i], M[i]);
    } else {
        float* dst = part + (size_t)blockIdx.x * NM;
        for (int i = tid; i < NM; i += 256) dst[i] = M[i];
    }
}

// Grid: RCHUNK * (NM/256) blocks. Chunk c sums nblocks/RCHUNK partial rows -> part2[c].
__global__ __launch_bounds__(256) void reduce_kernel(
    const float* __restrict__ part, float* __restrict__ part2, int nblocks)
{
    const int c = blockIdx.x & (RCHUNK - 1);
    const int g = blockIdx.x / RCHUNK;
    const int o = g * 256 + threadIdx.x;           // [0, NM)
    const int rpc = (nblocks + RCHUNK - 1) / RCHUNK;
    const int b0 = c * rpc;
    float s = 0.0f;
    for (int i = 0; i < rpc; ++i) {
        const int b = b0 + i;
        if (b < nblocks) s += part[(size_t)b * NM + o];
    }
    part2[(size_t)c * NM + o] = s;
}

// Grid: B blocks; block k evaluates bin k from the windowed sub-bucket moments.
__global__ __launch_bounds__(256) void finalize_kernel(
    const float* __restrict__ r_list, const float* __restrict__ cell,
    const float* __restrict__ partR, float* __restrict__ out,
    int B, int F, int nrows)
{
    __shared__ float Mred[NMOM * NB_MAX];
    __shared__ float red[256];
    const int k = blockIdx.x;
    if (k >= B) return;
    const int tid = threadIdx.x;

    const float r = r_list[k];
    const float L = cell[0];
    const float inv_delta = (2.0f * (float)NSUB) / L;
    const float delta = L / (2.0f * (float)NSUB);

    int blo = (int)((r - WIN_EVAL) * inv_delta);
    if (blo < 0) blo = 0;
    int bhi = (int)((r + WIN_EVAL) * inv_delta);
    if (bhi > NSUB - 1) bhi = NSUB - 1;
    int nb = bhi - blo + 1;
    if (nb > NB_MAX) nb = NB_MAX;                  // defensive; 98 for L=24

    // cooperative reduce of the window's moments across nrows partial rows
    for (int o = tid; o < NMOM * nb; o += 256) {
        const int m = o / nb;
        const int bo = o - m * nb;
        float ssum = 0.0f;
        for (int ch = 0; ch < nrows; ++ch)
            ssum += partR[(size_t)ch * NM + m * NSUB + blo + bo];
        Mred[o] = ssum;
    }
    __syncthreads();

    // per-sub-bucket Taylor reconstruction: f(c+eps) = f(c) * Hermite series in u=c-r
    float acc = 0.0f;
    if (tid < nb) {
        const int b = blo + tid;
        const float m0 = Mred[tid];
        const float m1 = Mred[nb + tid];
        const float m2 = Mred[2 * nb + tid];
        const float m3 = Mred[3 * nb + tid];
        const float m4 = Mred[4 * nb + tid];
        const float u  = fmaf((float)b + 0.5f, delta, -r);
        const float u2 = u * u;
        const float t  = __expf(-50.0f * u2);
        float ssum = m0;
        ssum = fmaf(m1, -100.0f * u, ssum);
        ssum = fmaf(m2, fmaf(5000.0f, u2, -50.0f), ssum);
        ssum = fmaf(m3, u * fmaf(-166666.671875f, u2, 5000.0f), ssum);
        ssum = fmaf(m4, fmaf(u2, fmaf(4166666.75f, u2, -250000.0f), 1250.0f), ssum);
        acc = t * ssum;
    }
    red[tid] = acc;
    __syncthreads();
    for (int off = 128; off > 0; off >>= 1) {
        if (tid < off) red[tid] += red[tid + off];
        __syncthreads();
    }
    if (tid == 0) {
        out[k] = r;                                    // output 0: r_list
        const float det = cell[0] * cell[4] * cell[8];
        const float rpv = r + 0.05f;
        const float rmv = r - 0.05f;
        const float v = (4.0f * (float)M_PI / 3.0f) * (rpv * rpv * rpv - rmv * rmv * rmv);
        const float inv_sqrt2pi = 0.3989422804014327f;
        const float h = red[0] * inv_sqrt2pi / (float)F;
        const float gr = h / v * det / (float)(N_ATOMS - 1) / (float)N_ATOMS * 2.0f;
        out[B + k] = gr;                               // output 1: gr
    }
}

extern "C" void kernel_launch(void* const* d_in, const int* in_sizes, int n_in,
                              void* d_out, int out_size, void* d_ws, size_t ws_size,
                              hipStream_t stream) {
    const float* traj   = (const float*)d_in[0];
    const float* cell   = (const float*)d_in[1];
    const float* r_list = (const float*)d_in[2];
    float* out  = (float*)d_out;
    float* part = (float*)d_ws;

    const int B = in_sizes[2];
    const int F = in_sizes[0] / (N_ATOMS * 3);
    const int nblocks = F * 64;

    const size_t need = ((size_t)nblocks + RCHUNK) * NM * sizeof(float);

    if (ws_size >= need) {
        // 3 dispatches: per-block moment partials, chunk-reduce, evaluate bins.
        float* part2 = part + (size_t)nblocks * NM;
        hipLaunchKernelGGL(pair_kernel, dim3(nblocks), dim3(256), 0, stream,
                           traj, cell, part, 0);
        hipLaunchKernelGGL(reduce_kernel, dim3(RCHUNK * (NM / 256)), dim3(256), 0, stream,
                           part, part2, nblocks);
        hipLaunchKernelGGL(finalize_kernel, dim3(B), dim3(256), 0, stream,
                           r_list, cell, part2, out, B, F, RCHUNK);
    } else {
        // Fallback: 16 replicated global-atomic moment histograms (240 KB), needs zeroing.
        hipLaunchKernelGGL(zero_kernel, dim3((16 * NM + 255) / 256), dim3(256), 0, stream,
                           part, 16 * NM);
        hipLaunchKernelGGL(pair_kernel, dim3(nblocks), dim3(256), 0, stream,
                           traj, cell, part, 1);
        hipLaunchKernelGGL(finalize_kernel, dim3(B), dim3(256), 0, stream,
                           r_list, cell, part, out, B, F, 16);
    }
}

// Round 2
// 94.695 us; speedup vs baseline: 1.3134x; 1.3134x over previous
//
#include <hip/hip_runtime.h>
#include <math.h>

#define N_ATOMS 512
#define NSUB 768                 // sub-buckets over [0, L/2); delta = 12/768 = 0.015625
#define NMOM 5                   // moments M0..M4 (Sum 1, eps, eps^2, eps^3, eps^4)
#define NM (NMOM * NSUB)         // 3840 floats per moment histogram
#define NREP 16                  // replicated global histograms (contention / parallelism)
#define WIN_EVAL 0.75f           // eval window; exp(-50*0.75^2) ~ 7e-13
#define NB_MAX 128               // max sub-buckets per bin window (96+2 for L=24)

__global__ void zero_kernel(float* p, int n) {
    int t = blockIdx.x * blockDim.x + threadIdx.x;
    if (t < n) p[t] = 0.0f;
}

// Grid: F * 64 blocks, 256 threads. Block = (frame, 4 bow-tie row-pairs) = 2048 pairs.
// Accumulates per-sub-bucket moment sums of eps = d - c_b in LDS, then atomically
// flushes into one of NREP replicated global moment histograms (240 KB, L2-resident).
__global__ __launch_bounds__(256) void pair_kernel(
    const float* __restrict__ traj, const float* __restrict__ cell,
    float* __restrict__ part)
{
    __shared__ float2 qxy[N_ATOMS];
    __shared__ float  qzs[N_ATOMS];
    __shared__ float  M[NM];     // SoA: M[m*NSUB + b]

    const int frame = blockIdx.x >> 6;
    const int sub   = blockIdx.x & 63;
    const int tid   = threadIdx.x;

    const float* q = traj + (size_t)frame * (N_ATOMS * 3);
    for (int a = tid; a < N_ATOMS; a += 256) {
        qxy[a] = make_float2(q[3 * a + 0], q[3 * a + 1]);
        qzs[a] = q[3 * a + 2];
    }
    for (int i = tid; i < NM; i += 256) M[i] = 0.0f;
    __syncthreads();

    const float L = cell[0];
    const float invL = 1.0f / L;
    const float cutoff_sq = 0.25f * L * L;
    const float inv_delta = (2.0f * (float)NSUB) / L;
    const float delta = L / (2.0f * (float)NSUB);

    #pragma unroll
    for (int s = 0; s < 8; ++s) {
        const int qidx = s * 256 + tid;            // [0, 2048)
        const int rp   = sub * 4 + (qidx >> 9);    // row-pair [0, 256)
        const int qq   = qidx & 511;
        const int lenA = 511 - rp;                 // row rp: j in (rp, 511]
        const bool inA = qq < lenA;
        const int i = inA ? rp : (510 - rp);       // partner row 510-rp
        const int j = inA ? (rp + 1 + qq) : qq;    // row B: j == qq (exact)
        const bool vp = !(rp == 255 && !inA);      // rp==255 pairs with itself: half only

        const float2 pj = qxy[j];
        const float2 pi = qxy[i];
        float dx = pj.x - pi.x;
        float dy = pj.y - pi.y;
        float dz = qzs[j] - qzs[i];
        dx -= L * floorf(dx * invL + 0.5f);
        dy -= L * floorf(dy * invL + 0.5f);
        dz -= L * floorf(dz * invL + 0.5f);
        const float d2 = dx * dx + dy * dy + dz * dz;

        if (vp && d2 < cutoff_sq && d2 != 0.0f) {
            const float d = sqrtf(d2);
            int b = (int)(d * inv_delta);
            if (b > NSUB - 1) b = NSUB - 1;
            const float eps = fmaf(-((float)b + 0.5f), delta, d);  // d - (b+0.5)*delta
            const float e2 = eps * eps;
            atomicAdd(&M[b],            1.0f);
            atomicAdd(&M[NSUB + b],     eps);
            atomicAdd(&M[2 * NSUB + b], e2);
            atomicAdd(&M[3 * NSUB + b], e2 * eps);
            atomicAdd(&M[4 * NSUB + b], e2 * e2);
        }
    }
    __syncthreads();

    float* dst = part + (size_t)(blockIdx.x & (NREP - 1)) * NM;
    for (int i = tid; i < NM; i += 256) atomicAdd(&dst[i], M[i]);
}

// Grid: B blocks; block k evaluates bin k from the windowed sub-bucket moments.
// NREP replica reduction is fully unrolled: 16 independent loads in flight per o.
__global__ __launch_bounds__(256) void finalize_kernel(
    const float* __restrict__ r_list, const float* __restrict__ cell,
    const float* __restrict__ partR, float* __restrict__ out,
    int B, int F)
{
    __shared__ float Mred[NMOM * NB_MAX];
    __shared__ float red[256];
    const int k = blockIdx.x;
    if (k >= B) return;
    const int tid = threadIdx.x;

    const float r = r_list[k];
    const float L = cell[0];
    const float inv_delta = (2.0f * (float)NSUB) / L;
    const float delta = L / (2.0f * (float)NSUB);

    int blo = (int)((r - WIN_EVAL) * inv_delta);
    if (blo < 0) blo = 0;
    int bhi = (int)((r + WIN_EVAL) * inv_delta);
    if (bhi > NSUB - 1) bhi = NSUB - 1;
    int nb = bhi - blo + 1;
    if (nb > NB_MAX) nb = NB_MAX;                  // defensive; 98 for L=24

    // cooperative reduce of the window's moments across the NREP replicas
    for (int o = tid; o < NMOM * nb; o += 256) {
        const int m = o / nb;
        const int bo = o - m * nb;
        const float* p0 = partR + m * NSUB + blo + bo;
        float s0 = 0.0f, s1 = 0.0f, s2 = 0.0f, s3 = 0.0f;
        #pragma unroll
        for (int ch = 0; ch < NREP; ch += 4) {
            s0 += p0[(size_t)(ch + 0) * NM];
            s1 += p0[(size_t)(ch + 1) * NM];
            s2 += p0[(size_t)(ch + 2) * NM];
            s3 += p0[(size_t)(ch + 3) * NM];
        }
        Mred[o] = (s0 + s1) + (s2 + s3);
    }
    __syncthreads();

    // per-sub-bucket Taylor reconstruction: f(c+eps) = f(c) * Hermite series in u=c-r
    float acc = 0.0f;
    if (tid < nb) {
        const int b = blo + tid;
        const float m0 = Mred[tid];
        const float m1 = Mred[nb + tid];
        const float m2 = Mred[2 * nb + tid];
        const float m3 = Mred[3 * nb + tid];
        const float m4 = Mred[4 * nb + tid];
        const float u  = fmaf((float)b + 0.5f, delta, -r);
        const float u2 = u * u;
        const float t  = __expf(-50.0f * u2);
        float ssum = m0;
        ssum = fmaf(m1, -100.0f * u, ssum);
        ssum = fmaf(m2, fmaf(5000.0f, u2, -50.0f), ssum);
        ssum = fmaf(m3, u * fmaf(-166666.671875f, u2, 5000.0f), ssum);
        ssum = fmaf(m4, fmaf(u2, fmaf(4166666.75f, u2, -250000.0f), 1250.0f), ssum);
        acc = t * ssum;
    }
    red[tid] = acc;
    __syncthreads();
    for (int off = 128; off > 0; off >>= 1) {
        if (tid < off) red[tid] += red[tid + off];
        __syncthreads();
    }
    if (tid == 0) {
        out[k] = r;                                    // output 0: r_list
        const float det = cell[0] * cell[4] * cell[8];
        const float rpv = r + 0.05f;
        const float rmv = r - 0.05f;
        const float v = (4.0f * (float)M_PI / 3.0f) * (rpv * rpv * rpv - rmv * rmv * rmv);
        const float inv_sqrt2pi = 0.3989422804014327f;
        const float h = red[0] * inv_sqrt2pi / (float)F;
        const float gr = h / v * det / (float)(N_ATOMS - 1) / (float)N_ATOMS * 2.0f;
        out[B + k] = gr;                               // output 1: gr
    }
}

extern "C" void kernel_launch(void* const* d_in, const int* in_sizes, int n_in,
                              void* d_out, int out_size, void* d_ws, size_t ws_size,
                              hipStream_t stream) {
    const float* traj   = (const float*)d_in[0];
    const float* cell   = (const float*)d_in[1];
    const float* r_list = (const float*)d_in[2];
    float* out  = (float*)d_out;
    float* part = (float*)d_ws;

    const int B = in_sizes[2];
    const int F = in_sizes[0] / (N_ATOMS * 3);
    const int nblocks = F * 64;

    // 3 dispatches: zero 240 KB, moment accumulation w/ replicated global
    // atomics, windowed Taylor evaluation (NREP unrolled).
    hipLaunchKernelGGL(zero_kernel, dim3((NREP * NM + 255) / 256), dim3(256), 0, stream,
                       part, NREP * NM);
    hipLaunchKernelGGL(pair_kernel, dim3(nblocks), dim3(256), 0, stream,
                       traj, cell, part);
    hipLaunchKernelGGL(finalize_kernel, dim3(B), dim3(256), 0, stream,
                       r_list, cell, part, out, B, F);
}

// Round 3
// 70.002 us; speedup vs baseline: 1.7767x; 1.3527x over previous
//
#include <hip/hip_runtime.h>
#include <math.h>

#define N_ATOMS 512
#define MAX_B 128
#define NBUCK 64
#define WIN 0.45f   // 4.5 sigma; peak truncated weight exp(-50*0.45^2)=4e-5 -> gr error ~2e-6,
                    // negligible vs 0.235 budget and below f32 noise.

__global__ void zero_kernel(float* p, int n) {
    int t = blockIdx.x * blockDim.x + threadIdx.x;
    if (t < n) p[t] = 0.0f;
}

// Grid: F * 64 blocks, 256 threads. Block = (frame, 4 bow-tie row-pairs) = 2048 pairs.
__global__ __launch_bounds__(256) void pair_kernel(
    const float* __restrict__ traj, const float* __restrict__ cell,
    const float* __restrict__ r_list, float* __restrict__ part,
    int B, int atomic_mode)
{
    __shared__ float2 qxy[N_ATOMS];
    __shared__ float  qzs[N_ATOMS];
    __shared__ float  dsorted[2048];
    __shared__ int    cnt[NBUCK];
    __shared__ int    start[NBUCK + 1];
    __shared__ int    cursor[NBUCK];
    __shared__ float  accbuf[256];

    const int frame = blockIdx.x >> 6;
    const int sub   = blockIdx.x & 63;
    const int tid   = threadIdx.x;

    const float* q = traj + (size_t)frame * (N_ATOMS * 3);
    for (int a = tid; a < N_ATOMS; a += 256) {
        qxy[a] = make_float2(q[3 * a + 0], q[3 * a + 1]);
        qzs[a] = q[3 * a + 2];
    }
    if (tid < NBUCK) cnt[tid] = 0;
    __syncthreads();

    const float L = cell[0];
    const float invL = 1.0f / L;
    const float cutoff_sq = 0.25f * L * L;
    const float inv_bw = (float)NBUCK / (0.5f * L);   // bucket = d * inv_bw in [0, NBUCK)

    // ---- phase 1a: distances + bucket counts (8 pairs per thread) ----
    float dval[8];
    int   dbuck[8];
    #pragma unroll
    for (int s = 0; s < 8; ++s) {
        const int qidx = s * 256 + tid;            // [0, 2048)
        const int rp   = sub * 4 + (qidx >> 9);    // row-pair [0, 256)
        const int qq   = qidx & 511;
        const int lenA = 511 - rp;                 // row rp: j in (rp, 511]
        const bool inA = qq < lenA;
        const int i = inA ? rp : (510 - rp);       // partner row 510-rp
        const int j = inA ? (rp + 1 + qq) : qq;    // row B: j == qq (exact)
        const bool vp = !(rp == 255 && !inA);      // rp==255 pairs with itself: half only

        const float2 pj = qxy[j];
        const float2 pi = qxy[i];
        float dx = pj.x - pi.x;
        float dy = pj.y - pi.y;
        float dz = qzs[j] - qzs[i];
        dx -= L * floorf(dx * invL + 0.5f);
        dy -= L * floorf(dy * invL + 0.5f);
        dz -= L * floorf(dz * invL + 0.5f);
        const float d2 = dx * dx + dy * dy + dz * dz;

        dbuck[s] = -1;
        dval[s]  = 0.0f;
        if (vp && d2 < cutoff_sq && d2 != 0.0f) {
            const float d = sqrtf(d2);
            int b = (int)(d * inv_bw);
            if (b > NBUCK - 1) b = NBUCK - 1;
            dval[s]  = d;
            dbuck[s] = b;
            atomicAdd(&cnt[b], 1);                 // native ds_add_u32
        }
    }
    __syncthreads();

    // ---- phase 1b: exclusive prefix scan of 64 bucket counts (one wave) ----
    if (tid < NBUCK) {
        const int v = cnt[tid];
        int incl = v;
        #pragma unroll
        for (int off = 1; off < NBUCK; off <<= 1) {
            const int n = __shfl_up(incl, off, 64);
            if (tid >= off) incl += n;
        }
        start[tid + 1] = incl;
        cursor[tid] = incl - v;
        if (tid == 0) start[0] = 0;
    }
    __syncthreads();

    // ---- phase 1c: scatter distances into bucket-sorted order ----
    #pragma unroll
    for (int s = 0; s < 8; ++s) {
        if (dbuck[s] >= 0) {
            const int pos = atomicAdd(&cursor[dbuck[s]], 1);
            dsorted[pos] = dval[s];
        }
    }
    __syncthreads();

    // ---- phase 2: bin-centric accumulation over windowed bucket range ----
    const int k = tid & 127;
    const int g = tid >> 7;
    float acc = 0.0f;
    if (k < B) {
        const float rk = r_list[k];
        const float c1 = -50.0f;
        const float c2 = 100.0f * rk;
        const float c3 = -50.0f * rk * rk;
        int blo = (int)(fmaxf((rk - WIN) * inv_bw, 0.0f));
        int bhi = (int)((rk + WIN) * inv_bw);
        if (bhi > NBUCK - 1) bhi = NBUCK - 1;
        const int lo = start[blo];
        const int hi = start[bhi + 1];
        int idx = lo + g;
        int nn = hi - idx;
        nn = (nn > 0) ? ((nn + 1) >> 1) : 0;       // elems for this lane at stride 2
        float acc1 = 0.0f;
        int m = nn >> 1;
        while (m-- > 0) {                          // 2-deep: both ds_reads in flight
            const float d0 = dsorted[idx];
            const float d1 = dsorted[idx + 2];
            idx += 4;
            acc  += __expf(fmaf(d0, fmaf(c1, d0, c2), c3));
            acc1 += __expf(fmaf(d1, fmaf(c1, d1, c2), c3));
        }
        if (nn & 1) {
            const float d0 = dsorted[idx];
            acc += __expf(fmaf(d0, fmaf(c1, d0, c2), c3));
        }
        acc += acc1;
    }
    accbuf[tid] = acc;
    __syncthreads();

    if (tid < 128) {
        const float v = accbuf[tid] + accbuf[tid + 128];
        if (atomic_mode) atomicAdd(&part[(blockIdx.x & 15) * MAX_B + tid], v);
        else             part[(size_t)blockIdx.x * MAX_B + tid] = v;
    }
}

// Grid: 128 blocks; block k reduces bin k over nrows partial histograms.
__global__ __launch_bounds__(256) void finalize_kernel(
    const float* __restrict__ r_list, const float* __restrict__ cell,
    const float* __restrict__ part, float* __restrict__ out,
    int B, int F, int nrows)
{
    __shared__ float red[256];
    const int k = blockIdx.x;
    if (k >= B) return;

    float s = 0.0f;
    for (int t = threadIdx.x; t < nrows; t += 256) s += part[(size_t)t * MAX_B + k];
    red[threadIdx.x] = s;
    __syncthreads();
    for (int off = 128; off > 0; off >>= 1) {
        if (threadIdx.x < off) red[threadIdx.x] += red[threadIdx.x + off];
        __syncthreads();
    }
    if (threadIdx.x == 0) {
        const float r = r_list[k];
        out[k] = r;                                    // output 0: r_list
        const float det = cell[0] * cell[4] * cell[8];
        const float rp = r + 0.05f;
        const float rm = r - 0.05f;
        const float v = (4.0f * (float)M_PI / 3.0f) * (rp * rp * rp - rm * rm * rm);
        const float inv_sqrt2pi = 0.3989422804014327f;
        const float h = red[0] * inv_sqrt2pi / (float)F;
        const float gr = h / v * det / (float)(N_ATOMS - 1) / (float)N_ATOMS * 2.0f;
        out[B + k] = gr;                               // output 1: gr
    }
}

extern "C" void kernel_launch(void* const* d_in, const int* in_sizes, int n_in,
                              void* d_out, int out_size, void* d_ws, size_t ws_size,
                              hipStream_t stream) {
    const float* traj   = (const float*)d_in[0];
    const float* cell   = (const float*)d_in[1];
    const float* r_list = (const float*)d_in[2];
    float* out  = (float*)d_out;
    float* part = (float*)d_ws;

    const int B = in_sizes[2];
    const int F = in_sizes[0] / (N_ATOMS * 3);
    const int nblocks = F * 64;

    const bool partials_fit =
        ws_size >= (size_t)nblocks * MAX_B * sizeof(float);

    if (partials_fit) {
        // 2 dispatches: unique-slot partials (no init needed), then reduce.
        hipLaunchKernelGGL(pair_kernel, dim3(nblocks), dim3(256), 0, stream,
                           traj, cell, r_list, part, B, 0);
        hipLaunchKernelGGL(finalize_kernel, dim3(MAX_B), dim3(256), 0, stream,
                           r_list, cell, part, out, B, F, nblocks);
    } else {
        // Fallback: 16 replicated atomic histograms (8 KB), needs zeroing.
        hipLaunchKernelGGL(zero_kernel, dim3(8), dim3(256), 0, stream,
                           part, 16 * MAX_B);
        hipLaunchKernelGGL(pair_kernel, dim3(nblocks), dim3(256), 0, stream,
                           traj, cell, r_list, part, B, 1);
        hipLaunchKernelGGL(finalize_kernel, dim3(MAX_B), dim3(256), 0, stream,
                           r_list, cell, part, out, B, F, 16);
    }
}